// Round 1
// 1081.168 us; speedup vs baseline: 1.1760x; 1.1760x over previous
//
#include <hip/hip_runtime.h>

// Problem: B=8, S=2048, D_IN=4096, D_OUT=4096, R=16
//   out[m,n] = (s[n]-1)*base[m,n] + s[n]*osora[m,n]
//   base  = x @ W^T  (M=16384,N=4096,K=4096)  -- bf16 MFMA
//   osora = (x@V^T * S) @ U^T * O = t @ W2^T,  W2[n,r]=O[n]S[r]U[n,r]
//   s[n]  = magnitude[n] / ||W[n,:] + W2[n,:]@V||   (fp32)
//
// R1: main GEMM ported from 128^2 2-barrier structure (ceiling ~900 TF) to the
// 256^2 8-phase counted-vmcnt schedule (T3+T4) + s_setprio (T5) + bijective
// XCD-chunked swizzle (T1). LDS addressing keeps the pre-swizzled-global-source
// XOR scheme (T2 equivalent; measured conflicts were 0.4% of cycles).

#define M_TOT 16384
#define N_TOT 4096
#define K_TOT 4096

typedef __attribute__((ext_vector_type(8))) short bf16x8;
typedef __attribute__((ext_vector_type(4))) float f32x4;

__device__ __forceinline__ unsigned short f2bf(float f){
  union { float f; unsigned int u; } v; v.f = f;
  unsigned int u = v.u;
  u += 0x7FFFu + ((u >> 16) & 1u);   // round-to-nearest-even
  return (unsigned short)(u >> 16);
}

__device__ __forceinline__ void async_lds16(const void* g, void* l){
  __builtin_amdgcn_global_load_lds(
      (const __attribute__((address_space(1))) unsigned int*)g,
      (__attribute__((address_space(3))) unsigned int*)l, 16, 0, 0);
}

// ---------------- cast fp32 -> bf16, 4 elems/thread ----------------
__global__ __launch_bounds__(256) void cast_f32_to_bf16_x4(
    const float* __restrict__ src, unsigned short* __restrict__ dst, int n4){
  int i = blockIdx.x * 256 + threadIdx.x;
  if (i >= n4) return;
  float4 v = ((const float4*)src)[i];
  ushort4 o;
  o.x = f2bf(v.x); o.y = f2bf(v.y); o.z = f2bf(v.z); o.w = f2bf(v.w);
  ((ushort4*)dst)[i] = o;
}

// ---------------- t = x @ V^T  -> bf16 [M][16] ----------------
__global__ __launch_bounds__(256) void tgemm_kernel(
    const unsigned short* __restrict__ xb, const unsigned short* __restrict__ vb,
    unsigned short* __restrict__ tb){
  int lane = threadIdx.x & 63;
  int wave = threadIdx.x >> 6;
  int quad = lane >> 4;
  int r16  = lane & 15;
  int m0 = (blockIdx.x * 4 + wave) * 16;
  const unsigned short* xptr = xb + (m0 + r16) * K_TOT + quad * 8;
  const unsigned short* vptr = vb + r16 * K_TOT + quad * 8;   // V row = rank index
  f32x4 acc = {0.f, 0.f, 0.f, 0.f};
  for (int k = 0; k < K_TOT; k += 32){
    bf16x8 a = *(const bf16x8*)(xptr + k);
    bf16x8 b = *(const bf16x8*)(vptr + k);
    acc = __builtin_amdgcn_mfma_f32_16x16x32_bf16(a, b, acc, 0, 0, 0);
  }
  // C/D: row(m) = quad*4+reg, col(r) = lane&15
  for (int reg = 0; reg < 4; reg++){
    int m = m0 + quad * 4 + reg;
    tb[m * 16 + r16] = f2bf(acc[reg]);
  }
}

// -------- weight_norm -> s, s-1, W2(bf16); 8 rows/block, V chunked in LDS --------
__global__ __launch_bounds__(256) void norm_kernel(
    const float* __restrict__ bw, const float* __restrict__ U,
    const float* __restrict__ S, const float* __restrict__ O,
    const float* __restrict__ mag, const float* __restrict__ V,
    float* __restrict__ s_out, float* __restrict__ sm1_out,
    unsigned short* __restrict__ w2b){
  __shared__ float Vl[16 * 1024];
  __shared__ float C8[8 * 16];
  __shared__ float red[8 * 4];
  int t = threadIdx.x;
  int lane = t & 63, wave = t >> 6;
  int n0 = blockIdx.x * 8;
  if (t < 128){
    int row = t >> 4, r = t & 15;
    int n = n0 + row;
    float c = O[n] * S[r] * U[n * 16 + r];
    C8[t] = c;
    w2b[n * 16 + r] = f2bf(c);
  }
  float nsq[8];
  for (int i = 0; i < 8; i++) nsq[i] = 0.f;
  for (int ch = 0; ch < 4; ch++){
    __syncthreads();                       // also guards C8 on first pass
    for (int j = 0; j < 16; j++){          // stage V[0:16][ch*1024 : +1024] fp32
      int idx4 = j * 256 + t;
      int r = idx4 >> 8, c4 = idx4 & 255;
      *(float4*)(Vl + r * 1024 + c4 * 4) =
          *(const float4*)(V + r * 4096 + ch * 1024 + c4 * 4);
    }
    __syncthreads();
    for (int row = 0; row < 8; row++){
      float4 b = *(const float4*)(bw + (n0 + row) * 4096 + ch * 1024 + t * 4);
      float a0 = 0.f, a1 = 0.f, a2 = 0.f, a3 = 0.f;
      for (int r = 0; r < 16; r++){
        float cr = C8[row * 16 + r];
        const float* vp = Vl + r * 1024 + t * 4;
        a0 += cr * vp[0]; a1 += cr * vp[1]; a2 += cr * vp[2]; a3 += cr * vp[3];
      }
      float d0 = b.x + a0, d1 = b.y + a1, d2 = b.z + a2, d3 = b.w + a3;
      nsq[row] += d0*d0 + d1*d1 + d2*d2 + d3*d3;
    }
  }
  for (int row = 0; row < 8; row++){
    float v = nsq[row];
    for (int off = 32; off > 0; off >>= 1) v += __shfl_down(v, off);
    if (lane == 0) red[row * 4 + wave] = v;
  }
  __syncthreads();
  if (t < 8){
    int n = n0 + t;
    float tot = red[t*4] + red[t*4+1] + red[t*4+2] + red[t*4+3];
    float s = mag[n] / sqrtf(tot);
    s_out[n] = s;
    sm1_out[n] = s - 1.0f;
  }
}

// ---------------- main GEMM + fused DoRA epilogue (256^2 8-phase) ----------------
// 256x256 tile, BK=64, 512 thr = 8 waves (2M x 4N), per-wave C = 128x64.
// LDS: 2 K-tile buffers x (A 32KB + B 32KB) = 128KB -> 1 block/CU.
// Per K-tile: 4 phases x {ds_read frags | 1 half-tile prefetch (2x gload_lds16)
//   -> s_barrier -> lgkmcnt(0) -> setprio(1) 16 MFMA setprio(0) -> s_barrier}.
// Quadrant order (m0-3/n0-1, m0-3/n2-3, m4-7/n0-1, m4-7/n2-3) retires the live
// buffer's B after phase 2 and A after phase 3; prefetch of tile kt+2/kt+3
// targets regions >=1 full barrier after their last read.
// Counted waits (in-flight ledger, 2 loads per half-tile):
//   end-P4: need prevP7(2)+prevP8(4)+P1(2)=8 oldest done, P3+P4=4 newer -> vmcnt(4)
//   end-P8: need P3..P6=8 oldest done,            P7(2)+P8(4)=6 newer -> vmcnt(6)
//   last iteration prefetches are predicated off -> P4 must drain: vmcnt(0).
__global__ __launch_bounds__(512, 2) void gemm_kernel(
    const unsigned short* __restrict__ A,   // x_bf16  [M][K]
    const unsigned short* __restrict__ B,   // w_bf16  [N][K]
    const unsigned short* __restrict__ Tb,  // t_bf16  [M][16]
    const unsigned short* __restrict__ W2b, // w2_bf16 [N][16]
    const float* __restrict__ s_arr, const float* __restrict__ sm1_arr,
    float* __restrict__ Cout){
  __shared__ unsigned short AL[2][16384];   // 2 x 256x64 bf16 = 64KB
  __shared__ unsigned short BL[2][16384];   // 64KB
  int tid  = threadIdx.x;
  int lane = tid & 63;
  int wave = tid >> 6;
  int wm   = wave >> 2;          // 0..1  (row half of C tile)
  int wn   = wave & 3;           // 0..3  (col quarter)
  int quad = lane >> 4;
  int r16  = lane & 15;
  int xm   = r16 & 7;

  // bijective XCD-chunked swizzle: 1024 wgs, 8 XCDs -> each XCD owns 8 bm x 16 bn
  int bid = blockIdx.x;
  int id  = (bid & 7) * 128 + (bid >> 3);
  int bm = id >> 4, bn = id & 15;
  int m0 = bm * 256, n0 = bn * 256;

  // staging: unit u in [0,1024) per 128x64 half-tile; row=u>>3, slot=u&7.
  // lane fetches xor-swizzled global octet ko = slot ^ (row&7); LDS write linear.
  int urow0 = tid >> 3,         uslot0 = tid & 7;
  int urow1 = (512+tid) >> 3,   uslot1 = (512+tid) & 7;
  int ko0 = uslot0 ^ (urow0 & 7);
  int ko1 = uslot1 ^ (urow1 & 7);
  int a_src0 = (m0 + urow0) * K_TOT + ko0 * 8;
  int a_src1 = (m0 + urow1) * K_TOT + ko1 * 8;
  int b_src0 = (n0 + urow0) * K_TOT + ko0 * 8;
  int b_src1 = (n0 + urow1) * K_TOT + ko1 * 8;
  int l_u0 = tid * 8;            // ushort offset inside 8192-ushort half region
  int l_u1 = (512 + tid) * 8;
  const int HSTEP = 128 * K_TOT; // global rows per half-tile

#define STG_A(bf_, h_, kt_) do{ \
    async_lds16(A + a_src0 + (h_)*HSTEP + (kt_)*64, &AL[bf_][(h_)*8192 + l_u0]); \
    async_lds16(A + a_src1 + (h_)*HSTEP + (kt_)*64, &AL[bf_][(h_)*8192 + l_u1]); }while(0)
#define STG_B(bf_, h_, kt_) do{ \
    async_lds16(B + b_src0 + (h_)*HSTEP + (kt_)*64, &BL[bf_][(h_)*8192 + l_u0]); \
    async_lds16(B + b_src1 + (h_)*HSTEP + (kt_)*64, &BL[bf_][(h_)*8192 + l_u1]); }while(0)

#define BAR()   __builtin_amdgcn_s_barrier()
#define LGKM0() asm volatile("s_waitcnt lgkmcnt(0)" ::: "memory")
#define VMW(n_) asm volatile("s_waitcnt vmcnt(" #n_ ")" ::: "memory")

  // fragment read bases (ushort units; row stride 64, 16 rows = 1024)
  int a_row = (wm * 128 + r16) * 64;
  int b_row = (wn * 64  + r16) * 64;
  int koA[2] = { (quad ^ xm) * 8, ((4 + quad) ^ xm) * 8 };

  f32x4 zf = {0.f, 0.f, 0.f, 0.f};
  f32x4 acc[8][4];
#pragma unroll
  for (int i = 0; i < 8; i++)
#pragma unroll
    for (int j = 0; j < 4; j++) acc[i][j] = zf;
  bf16x8 af[4][2], bA[2][2], bB[2][2];

#define RD_A(bf_, mb_) do{ _Pragma("unroll") \
    for (int mf = 0; mf < 4; ++mf){ _Pragma("unroll") \
      for (int ks = 0; ks < 2; ++ks) \
        af[mf][ks] = *(const bf16x8*)(&AL[bf_][a_row + ((mb_)+mf)*1024 + koA[ks]]); } }while(0)
#define RD_B(bf_, dst_, nb_) do{ _Pragma("unroll") \
    for (int nf = 0; nf < 2; ++nf){ _Pragma("unroll") \
      for (int ks = 0; ks < 2; ++ks) \
        dst_[nf][ks] = *(const bf16x8*)(&BL[bf_][b_row + ((nb_)+nf)*1024 + koA[ks]]); } }while(0)
#define MMQ(mb_, bset_, nb_) do{ _Pragma("unroll") \
    for (int ks = 0; ks < 2; ++ks){ _Pragma("unroll") \
      for (int mf = 0; mf < 4; ++mf){ _Pragma("unroll") \
        for (int nf = 0; nf < 2; ++nf) \
          acc[(mb_)+mf][(nb_)+nf] = __builtin_amdgcn_mfma_f32_16x16x32_bf16( \
              af[mf][ks], bset_[nf][ks], acc[(mb_)+mf][(nb_)+nf], 0, 0, 0); } } }while(0)

  // prologue: tile0 -> buf0 (8 loads), tile1 B0,B1,A0 -> buf1 (6 loads)
  STG_A(0, 0, 0); STG_A(0, 1, 0); STG_B(0, 0, 0); STG_B(0, 1, 0);
  STG_B(1, 0, 1); STG_B(1, 1, 1); STG_A(1, 0, 1);
  VMW(6);                         // oldest 8 (tile0) arrived
  BAR();

#pragma unroll 1
  for (int i = 0; i < 32; ++i){
    int kt = 2 * i;
    int pf = (i < 31);            // tiles kt+2 / kt+3 exist

    // P1: Q0 buf0 (m0-3 x n0-1); stage A-half1 of tile kt+1 -> buf1
    RD_A(0, 0); RD_B(0, bA, 0);
    STG_A(1, 1, kt + 1);
    BAR(); LGKM0();
    __builtin_amdgcn_s_setprio(1); MMQ(0, bA, 0); __builtin_amdgcn_s_setprio(0);
    BAR();
    // P2: Q1 buf0 (m0-3 x n2-3)
    RD_B(0, bB, 2);
    BAR(); LGKM0();
    __builtin_amdgcn_s_setprio(1); MMQ(0, bB, 2); __builtin_amdgcn_s_setprio(0);
    BAR();
    // P3: Q2 buf0 (m4-7 x n0-1); B of buf0 retired -> stage B-half0 tile kt+2
    RD_A(0, 4);
    if (pf) STG_B(0, 0, kt + 2);
    BAR(); LGKM0();
    __builtin_amdgcn_s_setprio(1); MMQ(4, bA, 0); __builtin_amdgcn_s_setprio(0);
    BAR();
    // P4: Q3 buf0 (m4-7 x n2-3); stage B-half1 tile kt+2; wait tile kt+1 arrived
    if (pf) STG_B(0, 1, kt + 2);
    BAR(); LGKM0();
    __builtin_amdgcn_s_setprio(1); MMQ(4, bB, 2); __builtin_amdgcn_s_setprio(0);
    if (pf) { VMW(4); } else { VMW(0); }
    BAR();
    // P5: Q0 buf1; A of buf0 retired -> stage A-half0 tile kt+2
    RD_A(1, 0); RD_B(1, bA, 0);
    if (pf) STG_A(0, 0, kt + 2);
    BAR(); LGKM0();
    __builtin_amdgcn_s_setprio(1); MMQ(0, bA, 0); __builtin_amdgcn_s_setprio(0);
    BAR();
    // P6: Q1 buf1; stage A-half1 tile kt+2
    RD_B(1, bB, 2);
    if (pf) STG_A(0, 1, kt + 2);
    BAR(); LGKM0();
    __builtin_amdgcn_s_setprio(1); MMQ(0, bB, 2); __builtin_amdgcn_s_setprio(0);
    BAR();
    // P7: Q2 buf1; B of buf1 retired -> stage B-half0 tile kt+3
    RD_A(1, 4);
    if (pf) STG_B(1, 0, kt + 3);
    BAR(); LGKM0();
    __builtin_amdgcn_s_setprio(1); MMQ(4, bA, 0); __builtin_amdgcn_s_setprio(0);
    BAR();
    // P8: Q3 buf1; stage B-half1 + A-half0 tile kt+3; wait tile kt+2 arrived
    if (pf) { STG_B(1, 1, kt + 3); STG_A(1, 0, kt + 3); }
    BAR(); LGKM0();
    __builtin_amdgcn_s_setprio(1); MMQ(4, bB, 2); __builtin_amdgcn_s_setprio(0);
    VMW(6);
    BAR();
  }

  // ---- epilogue: out = (s-1)*acc + s*(t @ W2^T) via zero-padded K=32 MFMA ----
  VMW(0);
  __syncthreads();   // all frag reads done before overwriting LDS
  {
    int row = tid >> 1, half = tid & 1;   // stage [256][16] bf16 + 16 zeros, stride 40
    uint4 z = {0u, 0u, 0u, 0u};
    unsigned short* Tp = &AL[0][0];
    unsigned short* Wp = &BL[0][0];
    *(uint4*)(Tp + row * 40 + half * 8)      = *(const uint4*)(Tb  + (m0 + row) * 16 + half * 8);
    *(uint4*)(Tp + row * 40 + 16 + half * 8) = z;
    *(uint4*)(Wp + row * 40 + half * 8)      = *(const uint4*)(W2b + (n0 + row) * 16 + half * 8);
    *(uint4*)(Wp + row * 40 + 16 + half * 8) = z;
  }
  __syncthreads();
#pragma unroll
  for (int nf = 0; nf < 4; ++nf){
    int nn = n0 + wn * 64 + nf * 16 + r16;
    float s   = s_arr[nn];
    float sm1 = sm1_arr[nn];
    bf16x8 b2 = *(const bf16x8*)(&BL[0][(wn * 64 + nf * 16 + r16) * 40 + quad * 8]);
#pragma unroll
    for (int mf = 0; mf < 8; ++mf){
      bf16x8 a2 = *(const bf16x8*)(&AL[0][(wm * 128 + mf * 16 + r16) * 40 + quad * 8]);
      f32x4 o2 = __builtin_amdgcn_mfma_f32_16x16x32_bf16(a2, b2, zf, 0, 0, 0);
      int mbase = m0 + wm * 128 + mf * 16 + quad * 4;
      float* cp = Cout + (long)mbase * N_TOT + nn;
      cp[0]         = sm1 * acc[mf][nf][0] + s * o2[0];
      cp[N_TOT]     = sm1 * acc[mf][nf][1] + s * o2[1];
      cp[2 * N_TOT] = sm1 * acc[mf][nf][2] + s * o2[2];
      cp[3 * N_TOT] = sm1 * acc[mf][nf][3] + s * o2[3];
    }
  }
#undef STG_A
#undef STG_B
#undef RD_A
#undef RD_B
#undef MMQ
#undef BAR
#undef LGKM0
#undef VMW
}

extern "C" void kernel_launch(void* const* d_in, const int* in_sizes, int n_in,
                              void* d_out, int out_size, void* d_ws, size_t ws_size,
                              hipStream_t stream){
  const float* x   = (const float*)d_in[0];
  const float* U   = (const float*)d_in[1];
  const float* V   = (const float*)d_in[2];
  const float* S   = (const float*)d_in[3];
  const float* O   = (const float*)d_in[4];
  const float* mag = (const float*)d_in[5];
  const float* bw  = (const float*)d_in[6];
  float* out = (float*)d_out;

  char* ws = (char*)d_ws;
  unsigned short* xb  = (unsigned short*)(ws);               // 134217728 B
  unsigned short* wb  = (unsigned short*)(ws + 134217728);   //  33554432 B
  unsigned short* vb  = (unsigned short*)(ws + 167772160);   //    131072 B
  unsigned short* tb  = (unsigned short*)(ws + 167903232);   //    524288 B
  unsigned short* w2b = (unsigned short*)(ws + 168427520);   //    131072 B
  float* s_arr   = (float*)(ws + 168558592);                 //     16384 B
  float* sm1_arr = (float*)(ws + 168574976);                 //     16384 B
  (void)in_sizes; (void)n_in; (void)out_size; (void)ws_size;

  cast_f32_to_bf16_x4<<<16384, 256, 0, stream>>>(bw, wb, 4194304);
  cast_f32_to_bf16_x4<<<64,    256, 0, stream>>>(V,  vb, 16384);
  cast_f32_to_bf16_x4<<<65536, 256, 0, stream>>>(x,  xb, 16777216);
  tgemm_kernel<<<256, 256, 0, stream>>>(xb, vb, tb);
  norm_kernel<<<512, 256, 0, stream>>>(bw, U, S, O, mag, V, s_arr, sm1_arr, w2b);
  gemm_kernel<<<1024, 512, 0, stream>>>(xb, wb, tb, w2b, s_arr, sm1_arr, out);
}

// Round 2
// 1046.238 us; speedup vs baseline: 1.2152x; 1.0334x over previous
//
#include <hip/hip_runtime.h>

// Problem: B=8, S=2048, D_IN=4096, D_OUT=4096, R=16
//   out[m,n] = (s[n]-1)*base[m,n] + s[n]*osora[m,n]
//   base  = x @ W^T  (M=16384,N=4096,K=4096)  -- bf16 MFMA
//   osora = (x@V^T * S) @ U^T * O = t @ W2^T,  W2[n,r]=O[n]S[r]U[n,r]
//   s[n]  = magnitude[n] / ||W[n,:] + W2[n,:]@V||   (fp32)
//
// R1: 256^2 8-phase counted-vmcnt schedule (T3+T4) + setprio (T5) + XCD swizzle.
//     808 -> 602 us, MfmaUtil 39%.
// R2: single-barrier phases. The pre-MFMA barrier + lgkmcnt(0) forced all 8
//     waves into lockstep, exposing the per-phase ds_read burst (P1/P5: 96KB/CU
//     ~750cy LDS pipe) + return latency with no MFMA in flight to cover it
//     (~810cy overhead/phase vs template's ~240). Keeping only the end-of-phase
//     barrier lets waves drift within a phase so one wave's ds_read/lgkm wait
//     overlaps the co-wave's MFMAs (the role-split setprio exists to arbitrate).
//     Correctness: each phase's ds_reads are consumed by its own MFMAs (compiler
//     emits the lgkm waits), so reads retire before each wave's end barrier;
//     every STG targets a region last read >=1 barrier earlier; per-wave vmcnt
//     ledger unchanged. Barriers via asm volatile w/ "memory" clobber so the
//     compiler cannot move LDS/VMEM ops across them.

#define M_TOT 16384
#define N_TOT 4096
#define K_TOT 4096

typedef __attribute__((ext_vector_type(8))) short bf16x8;
typedef __attribute__((ext_vector_type(4))) float f32x4;

__device__ __forceinline__ unsigned short f2bf(float f){
  union { float f; unsigned int u; } v; v.f = f;
  unsigned int u = v.u;
  u += 0x7FFFu + ((u >> 16) & 1u);   // round-to-nearest-even
  return (unsigned short)(u >> 16);
}

__device__ __forceinline__ void async_lds16(const void* g, void* l){
  __builtin_amdgcn_global_load_lds(
      (const __attribute__((address_space(1))) unsigned int*)g,
      (__attribute__((address_space(3))) unsigned int*)l, 16, 0, 0);
}

// ---------------- cast fp32 -> bf16, 4 elems/thread ----------------
__global__ __launch_bounds__(256) void cast_f32_to_bf16_x4(
    const float* __restrict__ src, unsigned short* __restrict__ dst, int n4){
  int i = blockIdx.x * 256 + threadIdx.x;
  if (i >= n4) return;
  float4 v = ((const float4*)src)[i];
  ushort4 o;
  o.x = f2bf(v.x); o.y = f2bf(v.y); o.z = f2bf(v.z); o.w = f2bf(v.w);
  ((ushort4*)dst)[i] = o;
}

// ---------------- t = x @ V^T  -> bf16 [M][16] ----------------
__global__ __launch_bounds__(256) void tgemm_kernel(
    const unsigned short* __restrict__ xb, const unsigned short* __restrict__ vb,
    unsigned short* __restrict__ tb){
  int lane = threadIdx.x & 63;
  int wave = threadIdx.x >> 6;
  int quad = lane >> 4;
  int r16  = lane & 15;
  int m0 = (blockIdx.x * 4 + wave) * 16;
  const unsigned short* xptr = xb + (m0 + r16) * K_TOT + quad * 8;
  const unsigned short* vptr = vb + r16 * K_TOT + quad * 8;   // V row = rank index
  f32x4 acc = {0.f, 0.f, 0.f, 0.f};
  for (int k = 0; k < K_TOT; k += 32){
    bf16x8 a = *(const bf16x8*)(xptr + k);
    bf16x8 b = *(const bf16x8*)(vptr + k);
    acc = __builtin_amdgcn_mfma_f32_16x16x32_bf16(a, b, acc, 0, 0, 0);
  }
  // C/D: row(m) = quad*4+reg, col(r) = lane&15
  for (int reg = 0; reg < 4; reg++){
    int m = m0 + quad * 4 + reg;
    tb[m * 16 + r16] = f2bf(acc[reg]);
  }
}

// -------- weight_norm -> s, s-1, W2(bf16); 8 rows/block, V chunked in LDS --------
__global__ __launch_bounds__(256) void norm_kernel(
    const float* __restrict__ bw, const float* __restrict__ U,
    const float* __restrict__ S, const float* __restrict__ O,
    const float* __restrict__ mag, const float* __restrict__ V,
    float* __restrict__ s_out, float* __restrict__ sm1_out,
    unsigned short* __restrict__ w2b){
  __shared__ float Vl[16 * 1024];
  __shared__ float C8[8 * 16];
  __shared__ float red[8 * 4];
  int t = threadIdx.x;
  int lane = t & 63, wave = t >> 6;
  int n0 = blockIdx.x * 8;
  if (t < 128){
    int row = t >> 4, r = t & 15;
    int n = n0 + row;
    float c = O[n] * S[r] * U[n * 16 + r];
    C8[t] = c;
    w2b[n * 16 + r] = f2bf(c);
  }
  float nsq[8];
  for (int i = 0; i < 8; i++) nsq[i] = 0.f;
  for (int ch = 0; ch < 4; ch++){
    __syncthreads();                       // also guards C8 on first pass
    for (int j = 0; j < 16; j++){          // stage V[0:16][ch*1024 : +1024] fp32
      int idx4 = j * 256 + t;
      int r = idx4 >> 8, c4 = idx4 & 255;
      *(float4*)(Vl + r * 1024 + c4 * 4) =
          *(const float4*)(V + r * 4096 + ch * 1024 + c4 * 4);
    }
    __syncthreads();
    for (int row = 0; row < 8; row++){
      float4 b = *(const float4*)(bw + (n0 + row) * 4096 + ch * 1024 + t * 4);
      float a0 = 0.f, a1 = 0.f, a2 = 0.f, a3 = 0.f;
      for (int r = 0; r < 16; r++){
        float cr = C8[row * 16 + r];
        const float* vp = Vl + r * 1024 + t * 4;
        a0 += cr * vp[0]; a1 += cr * vp[1]; a2 += cr * vp[2]; a3 += cr * vp[3];
      }
      float d0 = b.x + a0, d1 = b.y + a1, d2 = b.z + a2, d3 = b.w + a3;
      nsq[row] += d0*d0 + d1*d1 + d2*d2 + d3*d3;
    }
  }
  for (int row = 0; row < 8; row++){
    float v = nsq[row];
    for (int off = 32; off > 0; off >>= 1) v += __shfl_down(v, off);
    if (lane == 0) red[row * 4 + wave] = v;
  }
  __syncthreads();
  if (t < 8){
    int n = n0 + t;
    float tot = red[t*4] + red[t*4+1] + red[t*4+2] + red[t*4+3];
    float s = mag[n] / sqrtf(tot);
    s_out[n] = s;
    sm1_out[n] = s - 1.0f;
  }
}

// ---------------- main GEMM + fused DoRA epilogue (256^2, 8-phase, 1 barrier/phase) ----
// 256x256 tile, BK=64, 512 thr = 8 waves (2M x 4N), per-wave C = 128x64.
// LDS: 2 K-tile buffers x (A 32KB + B 32KB) = 128KB -> 1 block/CU.
// Per phase: {ds_read frags | stage half-tile | [VMW @P4/P8] | setprio(1) 16 MFMA
//             setprio(0) | s_barrier(+compiler fence)}.
// Each phase's ds_reads feed its own MFMAs -> compiler lgkm waits retire them
// before the wave's end barrier; stages target regions retired >=1 barrier ago.
// Counted waits (per-wave ledger, 2 loads per half-tile):
//   end-P4: prevP7(2)+prevP8(4)+P1(2)=8 oldest done, P3+P4=4 newer -> vmcnt(4)
//   end-P8: P3..P6=8 oldest done,           P7(2)+P8(4)=6 newer -> vmcnt(6)
//   last iteration prefetches predicated off -> P4 drains: vmcnt(0).
__global__ __launch_bounds__(512, 2) void gemm_kernel(
    const unsigned short* __restrict__ A,   // x_bf16  [M][K]
    const unsigned short* __restrict__ B,   // w_bf16  [N][K]
    const unsigned short* __restrict__ Tb,  // t_bf16  [M][16]
    const unsigned short* __restrict__ W2b, // w2_bf16 [N][16]
    const float* __restrict__ s_arr, const float* __restrict__ sm1_arr,
    float* __restrict__ Cout){
  __shared__ unsigned short AL[2][16384];   // 2 x 256x64 bf16 = 64KB
  __shared__ unsigned short BL[2][16384];   // 64KB
  int tid  = threadIdx.x;
  int lane = tid & 63;
  int wave = tid >> 6;
  int wm   = wave >> 2;          // 0..1  (row half of C tile)
  int wn   = wave & 3;           // 0..3  (col quarter)
  int quad = lane >> 4;
  int r16  = lane & 15;
  int xm   = r16 & 7;

  // bijective XCD-chunked swizzle: 1024 wgs, 8 XCDs -> each XCD owns 8 bm x 16 bn
  int bid = blockIdx.x;
  int id  = (bid & 7) * 128 + (bid >> 3);
  int bm = id >> 4, bn = id & 15;
  int m0 = bm * 256, n0 = bn * 256;

  // staging: unit u in [0,1024) per 128x64 half-tile; row=u>>3, slot=u&7.
  // lane fetches xor-swizzled global octet ko = slot ^ (row&7); LDS write linear.
  int urow0 = tid >> 3,         uslot0 = tid & 7;
  int urow1 = (512+tid) >> 3,   uslot1 = (512+tid) & 7;
  int ko0 = uslot0 ^ (urow0 & 7);
  int ko1 = uslot1 ^ (urow1 & 7);
  int a_src0 = (m0 + urow0) * K_TOT + ko0 * 8;
  int a_src1 = (m0 + urow1) * K_TOT + ko1 * 8;
  int b_src0 = (n0 + urow0) * K_TOT + ko0 * 8;
  int b_src1 = (n0 + urow1) * K_TOT + ko1 * 8;
  int l_u0 = tid * 8;            // ushort offset inside 8192-ushort half region
  int l_u1 = (512 + tid) * 8;
  const int HSTEP = 128 * K_TOT; // global rows per half-tile

#define STG_A(bf_, h_, kt_) do{ \
    async_lds16(A + a_src0 + (h_)*HSTEP + (kt_)*64, &AL[bf_][(h_)*8192 + l_u0]); \
    async_lds16(A + a_src1 + (h_)*HSTEP + (kt_)*64, &AL[bf_][(h_)*8192 + l_u1]); }while(0)
#define STG_B(bf_, h_, kt_) do{ \
    async_lds16(B + b_src0 + (h_)*HSTEP + (kt_)*64, &BL[bf_][(h_)*8192 + l_u0]); \
    async_lds16(B + b_src1 + (h_)*HSTEP + (kt_)*64, &BL[bf_][(h_)*8192 + l_u1]); }while(0)

// end-of-phase barrier WITH compiler memory fence: LDS/VMEM ops must not be
// scheduled across it (bare __builtin s_barrier is not an optimizer fence).
#define BARF()  asm volatile("s_barrier" ::: "memory")
#define VMW(n_) asm volatile("s_waitcnt vmcnt(" #n_ ")" ::: "memory")

  // fragment read bases (ushort units; row stride 64, 16 rows = 1024)
  int a_row = (wm * 128 + r16) * 64;
  int b_row = (wn * 64  + r16) * 64;
  int koA[2] = { (quad ^ xm) * 8, ((4 + quad) ^ xm) * 8 };

  f32x4 zf = {0.f, 0.f, 0.f, 0.f};
  f32x4 acc[8][4];
#pragma unroll
  for (int i = 0; i < 8; i++)
#pragma unroll
    for (int j = 0; j < 4; j++) acc[i][j] = zf;
  bf16x8 af[4][2], bA[2][2], bB[2][2];

#define RD_A(bf_, mb_) do{ _Pragma("unroll") \
    for (int mf = 0; mf < 4; ++mf){ _Pragma("unroll") \
      for (int ks = 0; ks < 2; ++ks) \
        af[mf][ks] = *(const bf16x8*)(&AL[bf_][a_row + ((mb_)+mf)*1024 + koA[ks]]); } }while(0)
#define RD_B(bf_, dst_, nb_) do{ _Pragma("unroll") \
    for (int nf = 0; nf < 2; ++nf){ _Pragma("unroll") \
      for (int ks = 0; ks < 2; ++ks) \
        dst_[nf][ks] = *(const bf16x8*)(&BL[bf_][b_row + ((nb_)+nf)*1024 + koA[ks]]); } }while(0)
#define MMQ(mb_, bset_, nb_) do{ _Pragma("unroll") \
    for (int ks = 0; ks < 2; ++ks){ _Pragma("unroll") \
      for (int mf = 0; mf < 4; ++mf){ _Pragma("unroll") \
        for (int nf = 0; nf < 2; ++nf) \
          acc[(mb_)+mf][(nb_)+nf] = __builtin_amdgcn_mfma_f32_16x16x32_bf16( \
              af[mf][ks], bset_[nf][ks], acc[(mb_)+mf][(nb_)+nf], 0, 0, 0); } } }while(0)

  // prologue: tile0 -> buf0 (8 loads), tile1 B0,B1,A0 -> buf1 (6 loads)
  STG_A(0, 0, 0); STG_A(0, 1, 0); STG_B(0, 0, 0); STG_B(0, 1, 0);
  STG_B(1, 0, 1); STG_B(1, 1, 1); STG_A(1, 0, 1);
  VMW(6);                         // oldest 8 (tile0) arrived
  BARF();

#pragma unroll 1
  for (int i = 0; i < 32; ++i){
    int kt = 2 * i;
    int pf = (i < 31);            // tiles kt+2 / kt+3 exist

    // P1: Q0 buf0 (m0-3 x n0-1); stage A-half1 of tile kt+1 -> buf1
    RD_A(0, 0); RD_B(0, bA, 0);
    STG_A(1, 1, kt + 1);
    __builtin_amdgcn_s_setprio(1); MMQ(0, bA, 0); __builtin_amdgcn_s_setprio(0);
    BARF();
    // P2: Q1 buf0 (m0-3 x n2-3)
    RD_B(0, bB, 2);
    __builtin_amdgcn_s_setprio(1); MMQ(0, bB, 2); __builtin_amdgcn_s_setprio(0);
    BARF();
    // P3: Q2 buf0 (m4-7 x n0-1); B of buf0 retired -> stage B-half0 tile kt+2
    RD_A(0, 4);
    if (pf) STG_B(0, 0, kt + 2);
    __builtin_amdgcn_s_setprio(1); MMQ(4, bA, 0); __builtin_amdgcn_s_setprio(0);
    BARF();
    // P4: Q3 buf0 (m4-7 x n2-3); stage B-half1 tile kt+2; wait tile kt+1 arrived
    if (pf) STG_B(0, 1, kt + 2);
    __builtin_amdgcn_s_setprio(1); MMQ(4, bB, 2); __builtin_amdgcn_s_setprio(0);
    if (pf) { VMW(4); } else { VMW(0); }
    BARF();
    // P5: Q0 buf1; A of buf0 retired -> stage A-half0 tile kt+2
    RD_A(1, 0); RD_B(1, bA, 0);
    if (pf) STG_A(0, 0, kt + 2);
    __builtin_amdgcn_s_setprio(1); MMQ(0, bA, 0); __builtin_amdgcn_s_setprio(0);
    BARF();
    // P6: Q1 buf1; stage A-half1 tile kt+2
    RD_B(1, bB, 2);
    if (pf) STG_A(0, 1, kt + 2);
    __builtin_amdgcn_s_setprio(1); MMQ(0, bB, 2); __builtin_amdgcn_s_setprio(0);
    BARF();
    // P7: Q2 buf1; B of buf1 retired -> stage B-half0 tile kt+3
    RD_A(1, 4);
    if (pf) STG_B(1, 0, kt + 3);
    __builtin_amdgcn_s_setprio(1); MMQ(4, bA, 0); __builtin_amdgcn_s_setprio(0);
    BARF();
    // P8: Q3 buf1; stage B-half1 + A-half0 tile kt+3; wait tile kt+2 arrived
    if (pf) { STG_B(1, 1, kt + 3); STG_A(1, 0, kt + 3); }
    __builtin_amdgcn_s_setprio(1); MMQ(4, bB, 2); __builtin_amdgcn_s_setprio(0);
    VMW(6);
    BARF();
  }

  // ---- epilogue: out = (s-1)*acc + s*(t @ W2^T) via zero-padded K=32 MFMA ----
  VMW(0);
  __syncthreads();   // all frag reads done before overwriting LDS
  {
    int row = tid >> 1, half = tid & 1;   // stage [256][16] bf16 + 16 zeros, stride 40
    uint4 z = {0u, 0u, 0u, 0u};
    unsigned short* Tp = &AL[0][0];
    unsigned short* Wp = &BL[0][0];
    *(uint4*)(Tp + row * 40 + half * 8)      = *(const uint4*)(Tb  + (m0 + row) * 16 + half * 8);
    *(uint4*)(Tp + row * 40 + 16 + half * 8) = z;
    *(uint4*)(Wp + row * 40 + half * 8)      = *(const uint4*)(W2b + (n0 + row) * 16 + half * 8);
    *(uint4*)(Wp + row * 40 + 16 + half * 8) = z;
  }
  __syncthreads();
#pragma unroll
  for (int nf = 0; nf < 4; ++nf){
    int nn = n0 + wn * 64 + nf * 16 + r16;
    float s   = s_arr[nn];
    float sm1 = sm1_arr[nn];
    bf16x8 b2 = *(const bf16x8*)(&BL[0][(wn * 64 + nf * 16 + r16) * 40 + quad * 8]);
#pragma unroll
    for (int mf = 0; mf < 8; ++mf){
      bf16x8 a2 = *(const bf16x8*)(&AL[0][(wm * 128 + mf * 16 + r16) * 40 + quad * 8]);
      f32x4 o2 = __builtin_amdgcn_mfma_f32_16x16x32_bf16(a2, b2, zf, 0, 0, 0);
      int mbase = m0 + wm * 128 + mf * 16 + quad * 4;
      float* cp = Cout + (long)mbase * N_TOT + nn;
      cp[0]         = sm1 * acc[mf][nf][0] + s * o2[0];
      cp[N_TOT]     = sm1 * acc[mf][nf][1] + s * o2[1];
      cp[2 * N_TOT] = sm1 * acc[mf][nf][2] + s * o2[2];
      cp[3 * N_TOT] = sm1 * acc[mf][nf][3] + s * o2[3];
    }
  }
#undef STG_A
#undef STG_B
#undef RD_A
#undef RD_B
#undef MMQ
#undef BARF
#undef VMW
}

extern "C" void kernel_launch(void* const* d_in, const int* in_sizes, int n_in,
                              void* d_out, int out_size, void* d_ws, size_t ws_size,
                              hipStream_t stream){
  const float* x   = (const float*)d_in[0];
  const float* U   = (const float*)d_in[1];
  const float* V   = (const float*)d_in[2];
  const float* S   = (const float*)d_in[3];
  const float* O   = (const float*)d_in[4];
  const float* mag = (const float*)d_in[5];
  const float* bw  = (const float*)d_in[6];
  float* out = (float*)d_out;

  char* ws = (char*)d_ws;
  unsigned short* xb  = (unsigned short*)(ws);               // 134217728 B
  unsigned short* wb  = (unsigned short*)(ws + 134217728);   //  33554432 B
  unsigned short* vb  = (unsigned short*)(ws + 167772160);   //    131072 B
  unsigned short* tb  = (unsigned short*)(ws + 167903232);   //    524288 B
  unsigned short* w2b = (unsigned short*)(ws + 168427520);   //    131072 B
  float* s_arr   = (float*)(ws + 168558592);                 //     16384 B
  float* sm1_arr = (float*)(ws + 168574976);                 //     16384 B
  (void)in_sizes; (void)n_in; (void)out_size; (void)ws_size;

  cast_f32_to_bf16_x4<<<16384, 256, 0, stream>>>(bw, wb, 4194304);
  cast_f32_to_bf16_x4<<<64,    256, 0, stream>>>(V,  vb, 16384);
  cast_f32_to_bf16_x4<<<65536, 256, 0, stream>>>(x,  xb, 16777216);
  tgemm_kernel<<<256, 256, 0, stream>>>(xb, vb, tb);
  norm_kernel<<<512, 256, 0, stream>>>(bw, U, S, O, mag, V, s_arr, sm1_arr, w2b);
  gemm_kernel<<<1024, 512, 0, stream>>>(xb, wb, tb, w2b, s_arr, sm1_arr, out);
}